// Round 3
// baseline (122.372 us; speedup 1.0000x reference)
//
#include <hip/hip_runtime.h>

#define F 128
#define NEG_SLOPE 0.2f
#define NG 8           // edge groups per block
#define GSZ 32         // lanes per group: 32 x float4 = 128 features
#define UNROLL 4

// Fused: el[u] = dot(x_src[u], attn_l) for u < n_src, er[v] = dot(x_dst[v], attn_r).
// One wave (64 lanes) per row, 2 floats per lane.
__global__ __launch_bounds__(256)
void node_logits_kernel(const float* __restrict__ x_src, const float* __restrict__ attn_l,
                        float* __restrict__ el, int n_src,
                        const float* __restrict__ x_dst, const float* __restrict__ attn_r,
                        float* __restrict__ er, int n_dst) {
    int gtid = blockIdx.x * blockDim.x + threadIdx.x;
    int row  = gtid >> 6;
    int lane = threadIdx.x & 63;
    const float* x; const float* attn; float* o; int r;
    if (row < n_src)              { x = x_src; attn = attn_l; o = el; r = row; }
    else if (row < n_src + n_dst) { x = x_dst; attn = attn_r; o = er; r = row - n_src; }
    else return;
    float2 xv = *reinterpret_cast<const float2*>(&x[(size_t)r * F + lane * 2]);
    float2 av = *reinterpret_cast<const float2*>(&attn[lane * 2]);
    float s = xv.x * av.x + xv.y * av.y;
    #pragma unroll
    for (int off = 32; off > 0; off >>= 1)
        s += __shfl_xor(s, off, 64);
    if (lane == 0) o[r] = s;
}

// Edge-parallel: w[e] = exp(leaky_relu(el[src]+er[dst])), plus CSR offsets from sorted dst_idx.
__global__ __launch_bounds__(256)
void edge_prep_kernel(const float* __restrict__ el, const float* __restrict__ er,
                      const int* __restrict__ src_idx, const int* __restrict__ dst_idx,
                      float* __restrict__ w, int* __restrict__ offs, int E, int n_dst) {
    int e = blockIdx.x * blockDim.x + threadIdx.x;
    if (e >= E) return;
    int s = src_idx[e];
    int d = dst_idx[e];
    float l = el[s] + er[d];
    l = l > 0.f ? l : NEG_SLOPE * l;
    w[e] = __expf(l);
    int prev = (e == 0) ? -1 : dst_idx[e - 1];
    for (int v = prev + 1; v <= d; ++v) offs[v] = e;
    if (e == E - 1)
        for (int v = d + 1; v <= n_dst; ++v) offs[v] = E;
}

// Fallback offsets-only builder (if workspace can't hold w).
__global__ __launch_bounds__(256)
void build_offsets_kernel(const int* __restrict__ dst_idx, int* __restrict__ offs,
                          int E, int n_dst) {
    int e = blockIdx.x * blockDim.x + threadIdx.x;
    if (e >= E) return;
    int d = dst_idx[e];
    int prev = (e == 0) ? -1 : dst_idx[e - 1];
    for (int v = prev + 1; v <= d; ++v) offs[v] = e;
    if (e == E - 1)
        for (int v = d + 1; v <= n_dst; ++v) offs[v] = E;
}

// One block (256 threads) per dst node. 8 groups x 32 lanes; UNROLL=4 independent
// edges per group per step -> 32 row gathers in flight. Lane owns 4 features.
template<bool USE_W>
__global__ __launch_bounds__(NG * GSZ)
void gat_aggregate_kernel(const float* __restrict__ x_src,
                          const float* __restrict__ wbuf,
                          const float* __restrict__ el,
                          const float* __restrict__ er,
                          const int* __restrict__ src_idx,
                          const int* __restrict__ offs,
                          float* __restrict__ out) {
    int v    = blockIdx.x;
    int tid  = threadIdx.x;
    int g    = tid >> 5;
    int lane = tid & 31;

    int start = offs[v];
    int end   = offs[v + 1];
    int count = end - start;
    float erv = USE_W ? 0.f : er[v];

    const float4* xs4 = reinterpret_cast<const float4*>(x_src);

    float4 a0 = make_float4(0.f,0.f,0.f,0.f), a1 = a0, a2 = a0, a3 = a0;
    float  d0 = 0.f, d1 = 0.f, d2 = 0.f, d3 = 0.f;

    int full = count & ~(UNROLL * NG - 1);   // multiple of 32
    for (int it = 0; it < full; it += UNROLL * NG) {
        int e0 = start + it + g;
        int e1 = e0 + NG, e2 = e0 + 2 * NG, e3 = e0 + 3 * NG;
        int s0 = src_idx[e0], s1 = src_idx[e1], s2 = src_idx[e2], s3 = src_idx[e3];
        float4 x0 = xs4[(size_t)s0 * (F/4) + lane];
        float4 x1 = xs4[(size_t)s1 * (F/4) + lane];
        float4 x2 = xs4[(size_t)s2 * (F/4) + lane];
        float4 x3 = xs4[(size_t)s3 * (F/4) + lane];
        float w0, w1, w2, w3;
        if (USE_W) {
            w0 = wbuf[e0]; w1 = wbuf[e1]; w2 = wbuf[e2]; w3 = wbuf[e3];
        } else {
            float l0 = el[s0] + erv, l1 = el[s1] + erv, l2 = el[s2] + erv, l3 = el[s3] + erv;
            l0 = l0 > 0.f ? l0 : NEG_SLOPE * l0;  l1 = l1 > 0.f ? l1 : NEG_SLOPE * l1;
            l2 = l2 > 0.f ? l2 : NEG_SLOPE * l2;  l3 = l3 > 0.f ? l3 : NEG_SLOPE * l3;
            w0 = __expf(l0); w1 = __expf(l1); w2 = __expf(l2); w3 = __expf(l3);
        }
        d0 += w0; d1 += w1; d2 += w2; d3 += w3;
        a0.x += w0*x0.x; a0.y += w0*x0.y; a0.z += w0*x0.z; a0.w += w0*x0.w;
        a1.x += w1*x1.x; a1.y += w1*x1.y; a1.z += w1*x1.z; a1.w += w1*x1.w;
        a2.x += w2*x2.x; a2.y += w2*x2.y; a2.z += w2*x2.z; a2.w += w2*x2.w;
        a3.x += w3*x3.x; a3.y += w3*x3.y; a3.z += w3*x3.z; a3.w += w3*x3.w;
    }
    // tail: stride-NG, one edge per group
    for (int e = start + full + g; e < end; e += NG) {
        int s = src_idx[e];
        float w;
        if (USE_W) w = wbuf[e];
        else {
            float l = el[s] + erv;
            l = l > 0.f ? l : NEG_SLOPE * l;
            w = __expf(l);
        }
        float4 x = xs4[(size_t)s * (F/4) + lane];
        d0 += w;
        a0.x += w*x.x; a0.y += w*x.y; a0.z += w*x.z; a0.w += w*x.w;
    }
    a0.x += a1.x + a2.x + a3.x;  a0.y += a1.y + a2.y + a3.y;
    a0.z += a1.z + a2.z + a3.z;  a0.w += a1.w + a2.w + a3.w;
    d0 += d1 + d2 + d3;

    __shared__ float4 lacc[NG][GSZ];
    __shared__ float  lden[NG];
    lacc[g][lane] = a0;
    if (lane == 0) lden[g] = d0;
    __syncthreads();

    if (g == 0) {
        float4 t  = lacc[0][lane];
        float  dd = lden[0];
        #pragma unroll
        for (int k = 1; k < NG; ++k) {
            float4 u = lacc[k][lane];
            t.x += u.x; t.y += u.y; t.z += u.z; t.w += u.w;
            dd += lden[k];
        }
        float inv = (count > 0) ? 1.f / dd : 0.f;
        reinterpret_cast<float4*>(out)[(size_t)v * (F/4) + lane] =
            make_float4(t.x * inv, t.y * inv, t.z * inv, t.w * inv);
    }
}

extern "C" void kernel_launch(void* const* d_in, const int* in_sizes, int n_in,
                              void* d_out, int out_size, void* d_ws, size_t ws_size,
                              hipStream_t stream) {
    const float* x_src   = (const float*)d_in[0];
    const float* x_dst   = (const float*)d_in[1];
    const float* attn_l  = (const float*)d_in[2];
    const float* attn_r  = (const float*)d_in[3];
    const int*   src_idx = (const int*)d_in[4];
    const int*   dst_idx = (const int*)d_in[5];

    int n_src = in_sizes[0] / F;   // 50000
    int n_dst = in_sizes[1] / F;   // 10000
    int E     = in_sizes[4];       // 1600000

    float* out  = (float*)d_out;
    float* el   = (float*)d_ws;                 // n_src floats
    float* er   = el + n_src;                   // n_dst floats
    int*   offs = (int*)(er + n_dst);           // n_dst+1 ints
    float* w    = (float*)(offs + n_dst + 1);   // E floats (if room)

    size_t need_w = ((size_t)n_src + n_dst + n_dst + 1 + E) * 4;
    bool use_w = ws_size >= need_w;

    {
        int rows = n_src + n_dst;
        int rows_per_block = 256 / 64;
        node_logits_kernel<<<(rows + rows_per_block - 1) / rows_per_block, 256, 0, stream>>>(
            x_src, attn_l, el, n_src, x_dst, attn_r, er, n_dst);
    }

    if (use_w) {
        edge_prep_kernel<<<(E + 255) / 256, 256, 0, stream>>>(el, er, src_idx, dst_idx,
                                                              w, offs, E, n_dst);
        gat_aggregate_kernel<true><<<n_dst, NG * GSZ, 0, stream>>>(
            x_src, w, el, er, src_idx, offs, out);
    } else {
        build_offsets_kernel<<<(E + 255) / 256, 256, 0, stream>>>(dst_idx, offs, E, n_dst);
        gat_aggregate_kernel<false><<<n_dst, NG * GSZ, 0, stream>>>(
            x_src, nullptr, el, er, src_idx, offs, out);
    }
}

// Round 4
// 93.444 us; speedup vs baseline: 1.3096x; 1.3096x over previous
//
#include <hip/hip_runtime.h>
#include <hip/hip_fp16.h>

#define F 128
#define NEG_SLOPE 0.2f
#define NG16 16     // 16-lane groups per 256-thread block (fp16 path)
#define NG32 8      // 32-lane groups (fp32 fallback)

// Fused: el[u] = dot(x_src[u], attn_l) AND fp16 conversion of x_src; er[v] = dot(x_dst[v], attn_r).
// One wave (64 lanes) per row, 2 floats per lane.
__global__ __launch_bounds__(256)
void logits_convert_kernel(const float* __restrict__ x_src, const float* __restrict__ attn_l,
                           float* __restrict__ el, __half2* __restrict__ xh, int n_src,
                           const float* __restrict__ x_dst, const float* __restrict__ attn_r,
                           float* __restrict__ er, int n_dst) {
    int gtid = blockIdx.x * blockDim.x + threadIdx.x;
    int row  = gtid >> 6;
    int lane = threadIdx.x & 63;
    if (row < n_src) {
        float2 xv = *reinterpret_cast<const float2*>(&x_src[(size_t)row * F + lane * 2]);
        float2 av = *reinterpret_cast<const float2*>(&attn_l[lane * 2]);
        if (xh) xh[(size_t)row * (F / 2) + lane] = __floats2half2_rn(xv.x, xv.y);
        float s = xv.x * av.x + xv.y * av.y;
        #pragma unroll
        for (int off = 32; off > 0; off >>= 1) s += __shfl_xor(s, off, 64);
        if (lane == 0) el[row] = s;
    } else if (row < n_src + n_dst) {
        int r = row - n_src;
        float2 xv = *reinterpret_cast<const float2*>(&x_dst[(size_t)r * F + lane * 2]);
        float2 av = *reinterpret_cast<const float2*>(&attn_r[lane * 2]);
        float s = xv.x * av.x + xv.y * av.y;
        #pragma unroll
        for (int off = 32; off > 0; off >>= 1) s += __shfl_xor(s, off, 64);
        if (lane == 0) er[r] = s;
    }
}

// fp16-gather aggregate: one block (256 thr) per dst node, 16 groups x 16 lanes.
// Lane owns 8 features (one 16B load/edge). Weights computed inline; segment
// bounds by binary search on sorted dst_idx. 2x unroll -> 32 edge gathers in flight.
__global__ __launch_bounds__(256)
void gat_aggregate_h_kernel(const __half2* __restrict__ xh,
                            const float* __restrict__ el,
                            const float* __restrict__ er,
                            const int* __restrict__ src_idx,
                            const int* __restrict__ dst_idx,
                            float* __restrict__ out, int E) {
    int v    = blockIdx.x;
    int tid  = threadIdx.x;
    int g    = tid >> 4;
    int lane = tid & 15;

    int lo = 0, hi = E;
    while (lo < hi) { int m = (lo + hi) >> 1; if (dst_idx[m] < v) lo = m + 1; else hi = m; }
    int start = lo;  hi = E;
    while (lo < hi) { int m = (lo + hi) >> 1; if (dst_idx[m] < v + 1) lo = m + 1; else hi = m; }
    int end = lo;
    int count = end - start;
    float erv = er[v];

    const float4* x4 = reinterpret_cast<const float4*>(xh);  // row stride: F/8 = 16 float4

    float a0[8], a1[8];
    #pragma unroll
    for (int k = 0; k < 8; ++k) { a0[k] = 0.f; a1[k] = 0.f; }
    float d0 = 0.f, d1 = 0.f;

    int full = count & ~(2 * NG16 - 1);   // multiple of 32
    for (int it = 0; it < full; it += 2 * NG16) {
        int e0 = start + it + g;
        int e1 = e0 + NG16;
        int s0 = src_idx[e0];
        int s1 = src_idx[e1];
        float4 r0 = x4[(size_t)s0 * (F / 8) + lane];
        float4 r1 = x4[(size_t)s1 * (F / 8) + lane];
        float l0 = el[s0] + erv, l1 = el[s1] + erv;
        l0 = l0 > 0.f ? l0 : NEG_SLOPE * l0;
        l1 = l1 > 0.f ? l1 : NEG_SLOPE * l1;
        float w0 = __expf(l0), w1 = __expf(l1);
        d0 += w0; d1 += w1;
        const __half2* h0 = reinterpret_cast<const __half2*>(&r0);
        const __half2* h1 = reinterpret_cast<const __half2*>(&r1);
        #pragma unroll
        for (int k = 0; k < 4; ++k) {
            float2 f0 = __half22float2(h0[k]);
            float2 f1 = __half22float2(h1[k]);
            a0[2*k]   += w0 * f0.x;  a0[2*k+1] += w0 * f0.y;
            a1[2*k]   += w1 * f1.x;  a1[2*k+1] += w1 * f1.y;
        }
    }
    for (int e = start + full + g; e < end; e += NG16) {
        int s = src_idx[e];
        float4 r = x4[(size_t)s * (F / 8) + lane];
        float l = el[s] + erv;
        l = l > 0.f ? l : NEG_SLOPE * l;
        float w = __expf(l);
        d0 += w;
        const __half2* h = reinterpret_cast<const __half2*>(&r);
        #pragma unroll
        for (int k = 0; k < 4; ++k) {
            float2 f = __half22float2(h[k]);
            a0[2*k]   += w * f.x;  a0[2*k+1] += w * f.y;
        }
    }
    #pragma unroll
    for (int k = 0; k < 8; ++k) a0[k] += a1[k];
    d0 += d1;

    __shared__ float part[NG16][F];
    __shared__ float lden[NG16];
    #pragma unroll
    for (int k = 0; k < 8; ++k) part[g][lane * 8 + k] = a0[k];
    if (lane == 0) lden[g] = d0;
    __syncthreads();

    if (tid < F) {
        float t = 0.f, dd = 0.f;
        #pragma unroll
        for (int k = 0; k < NG16; ++k) { t += part[k][tid]; dd += lden[k]; }
        out[(size_t)v * F + tid] = (count > 0) ? t / dd : 0.f;
    }
}

// fp32 fallback (no workspace for xh): 8 groups x 32 lanes, lane owns 4 feats.
__global__ __launch_bounds__(256)
void gat_aggregate_f_kernel(const float* __restrict__ x_src,
                            const float* __restrict__ el,
                            const float* __restrict__ er,
                            const int* __restrict__ src_idx,
                            const int* __restrict__ dst_idx,
                            float* __restrict__ out, int E) {
    int v    = blockIdx.x;
    int tid  = threadIdx.x;
    int g    = tid >> 5;
    int lane = tid & 31;

    int lo = 0, hi = E;
    while (lo < hi) { int m = (lo + hi) >> 1; if (dst_idx[m] < v) lo = m + 1; else hi = m; }
    int start = lo;  hi = E;
    while (lo < hi) { int m = (lo + hi) >> 1; if (dst_idx[m] < v + 1) lo = m + 1; else hi = m; }
    int end = lo;
    int count = end - start;
    float erv = er[v];

    const float4* xs4 = reinterpret_cast<const float4*>(x_src);
    float4 a0 = make_float4(0.f,0.f,0.f,0.f), a1 = a0;
    float d0 = 0.f, d1 = 0.f;

    int full = count & ~(2 * NG32 - 1);
    for (int it = 0; it < full; it += 2 * NG32) {
        int e0 = start + it + g, e1 = e0 + NG32;
        int s0 = src_idx[e0], s1 = src_idx[e1];
        float4 x0 = xs4[(size_t)s0 * (F/4) + lane];
        float4 x1 = xs4[(size_t)s1 * (F/4) + lane];
        float l0 = el[s0] + erv, l1 = el[s1] + erv;
        l0 = l0 > 0.f ? l0 : NEG_SLOPE * l0;
        l1 = l1 > 0.f ? l1 : NEG_SLOPE * l1;
        float w0 = __expf(l0), w1 = __expf(l1);
        d0 += w0; d1 += w1;
        a0.x += w0*x0.x; a0.y += w0*x0.y; a0.z += w0*x0.z; a0.w += w0*x0.w;
        a1.x += w1*x1.x; a1.y += w1*x1.y; a1.z += w1*x1.z; a1.w += w1*x1.w;
    }
    for (int e = start + full + g; e < end; e += NG32) {
        int s = src_idx[e];
        float l = el[s] + erv;
        l = l > 0.f ? l : NEG_SLOPE * l;
        float w = __expf(l);
        float4 x = xs4[(size_t)s * (F/4) + lane];
        d0 += w;
        a0.x += w*x.x; a0.y += w*x.y; a0.z += w*x.z; a0.w += w*x.w;
    }
    a0.x += a1.x; a0.y += a1.y; a0.z += a1.z; a0.w += a1.w;
    d0 += d1;

    __shared__ float4 lacc[NG32][32];
    __shared__ float  lden[NG32];
    lacc[g][lane] = a0;
    if (lane == 0) lden[g] = d0;
    __syncthreads();

    if (g == 0) {
        float4 t = lacc[0][lane];
        float dd = lden[0];
        #pragma unroll
        for (int k = 1; k < NG32; ++k) {
            float4 u = lacc[k][lane];
            t.x += u.x; t.y += u.y; t.z += u.z; t.w += u.w;
            dd += lden[k];
        }
        float inv = (count > 0) ? 1.f / dd : 0.f;
        reinterpret_cast<float4*>(out)[(size_t)v * (F/4) + lane] =
            make_float4(t.x * inv, t.y * inv, t.z * inv, t.w * inv);
    }
}

extern "C" void kernel_launch(void* const* d_in, const int* in_sizes, int n_in,
                              void* d_out, int out_size, void* d_ws, size_t ws_size,
                              hipStream_t stream) {
    const float* x_src   = (const float*)d_in[0];
    const float* x_dst   = (const float*)d_in[1];
    const float* attn_l  = (const float*)d_in[2];
    const float* attn_r  = (const float*)d_in[3];
    const int*   src_idx = (const int*)d_in[4];
    const int*   dst_idx = (const int*)d_in[5];

    int n_src = in_sizes[0] / F;   // 50000
    int n_dst = in_sizes[1] / F;   // 10000
    int E     = in_sizes[4];       // 1600000

    float* out = (float*)d_out;
    float* el  = (float*)d_ws;                 // n_src floats
    float* er  = el + n_src;                   // n_dst floats
    uintptr_t p = (uintptr_t)(er + n_dst);
    p = (p + 15) & ~(uintptr_t)15;             // 16B-align for float4 reads
    __half2* xh = (__half2*)p;                 // n_src * F halves

    size_t need = (p - (uintptr_t)d_ws) + (size_t)n_src * F * sizeof(__half);
    bool fp16ok = ws_size >= need;

    {
        int rows = n_src + n_dst;
        int rpb = 256 / 64;
        logits_convert_kernel<<<(rows + rpb - 1) / rpb, 256, 0, stream>>>(
            x_src, attn_l, el, fp16ok ? xh : nullptr, n_src, x_dst, attn_r, er, n_dst);
    }

    if (fp16ok) {
        gat_aggregate_h_kernel<<<n_dst, 256, 0, stream>>>(xh, el, er, src_idx, dst_idx, out, E);
    } else {
        gat_aggregate_f_kernel<<<n_dst, 256, 0, stream>>>(x_src, el, er, src_idx, dst_idx, out, E);
    }
}

// Round 5
// 86.934 us; speedup vs baseline: 1.4076x; 1.0749x over previous
//
#include <hip/hip_runtime.h>
#include <hip/hip_fp16.h>

#define F 128
#define NEG_SLOPE 0.2f

// Fused prep: blocks [0, nlog) -> per-node logits (+fp16 convert of x_src rows);
// blocks [nlog, nlog+noff) -> CSR offsets from sorted dst_idx.
__global__ __launch_bounds__(256)
void prep_kernel(const float* __restrict__ x_src, const float* __restrict__ attn_l,
                 float* __restrict__ el, __half2* __restrict__ xh, int n_src,
                 const float* __restrict__ x_dst, const float* __restrict__ attn_r,
                 float* __restrict__ er, int n_dst,
                 const int* __restrict__ dst_idx, int* __restrict__ offs, int E,
                 int nlog) {
    if ((int)blockIdx.x < nlog) {
        int row  = blockIdx.x * 4 + (threadIdx.x >> 6);
        int lane = threadIdx.x & 63;
        if (row < n_src) {
            float2 xv = *reinterpret_cast<const float2*>(&x_src[(size_t)row * F + lane * 2]);
            float2 av = *reinterpret_cast<const float2*>(&attn_l[lane * 2]);
            if (xh) xh[(size_t)row * (F / 2) + lane] = __floats2half2_rn(xv.x, xv.y);
            float s = xv.x * av.x + xv.y * av.y;
            #pragma unroll
            for (int o = 32; o > 0; o >>= 1) s += __shfl_xor(s, o, 64);
            if (lane == 0) el[row] = s;
        } else if (row < n_src + n_dst) {
            int r = row - n_src;
            float2 xv = *reinterpret_cast<const float2*>(&x_dst[(size_t)r * F + lane * 2]);
            float2 av = *reinterpret_cast<const float2*>(&attn_r[lane * 2]);
            float s = xv.x * av.x + xv.y * av.y;
            #pragma unroll
            for (int o = 32; o > 0; o >>= 1) s += __shfl_xor(s, o, 64);
            if (lane == 0) er[r] = s;
        }
    } else {
        int e = ((int)blockIdx.x - nlog) * 256 + threadIdx.x;
        if (e >= E) return;
        int d = dst_idx[e];
        int prev = (e == 0) ? -1 : dst_idx[e - 1];
        for (int v = prev + 1; v <= d; ++v) offs[v] = e;
        if (e == E - 1)
            for (int v = d + 1; v <= n_dst; ++v) offs[v] = E;
    }
}

// One 64-lane wave per dst node. 4 sub-groups of 16 lanes stride the node's edge
// list; lane owns 8 features (16B fp16 load per edge). Unroll 2 -> 8 independent
// row gathers in flight per wave. No LDS, no syncthreads, no search.
// Cross-group merge: 2 shfl_xor rounds. VGPR stays <= 64 -> full occupancy.
template<bool H>
__global__ __launch_bounds__(256)
void gat_aggregate_kernel(const __half2* __restrict__ xh,
                          const float* __restrict__ x_src,
                          const float* __restrict__ el,
                          const float* __restrict__ er,
                          const int* __restrict__ src_idx,
                          const int* __restrict__ offs,
                          float* __restrict__ out, int n_dst) {
    int v = blockIdx.x * 4 + (threadIdx.x >> 6);
    if (v >= n_dst) return;
    int lane = threadIdx.x & 63;
    int g    = lane >> 4;          // sub-group 0..3
    int l16  = lane & 15;          // lane within sub-group

    int start = offs[v];
    int end   = offs[v + 1];
    int count = end - start;
    float erv = er[v];

    const float4* x4h = reinterpret_cast<const float4*>(xh);     // 16 float4 / row
    const float4* x4f = reinterpret_cast<const float4*>(x_src);  // 32 float4 / row

    float a0[8], a1[8];
    #pragma unroll
    for (int k = 0; k < 8; ++k) { a0[k] = 0.f; a1[k] = 0.f; }
    float d0 = 0.f, d1 = 0.f;

    int full = count & ~7;          // wave covers 8 edges per iter (4 groups x 2)
    for (int it = 0; it < full; it += 8) {
        int e0 = start + it + g;
        int e1 = e0 + 4;
        int s0 = src_idx[e0];
        int s1 = src_idx[e1];
        float l0 = el[s0] + erv, l1 = el[s1] + erv;
        l0 = l0 > 0.f ? l0 : NEG_SLOPE * l0;
        l1 = l1 > 0.f ? l1 : NEG_SLOPE * l1;
        float w0 = __expf(l0), w1 = __expf(l1);
        d0 += w0; d1 += w1;
        if (H) {
            float4 r0 = x4h[(size_t)s0 * (F / 8) + l16];
            float4 r1 = x4h[(size_t)s1 * (F / 8) + l16];
            const __half2* h0 = reinterpret_cast<const __half2*>(&r0);
            const __half2* h1 = reinterpret_cast<const __half2*>(&r1);
            #pragma unroll
            for (int k = 0; k < 4; ++k) {
                float2 f0 = __half22float2(h0[k]);
                float2 f1 = __half22float2(h1[k]);
                a0[2*k]   += w0 * f0.x;  a0[2*k+1] += w0 * f0.y;
                a1[2*k]   += w1 * f1.x;  a1[2*k+1] += w1 * f1.y;
            }
        } else {
            float4 p0 = x4f[(size_t)s0 * (F / 4) + l16 * 2];
            float4 q0 = x4f[(size_t)s0 * (F / 4) + l16 * 2 + 1];
            float4 p1 = x4f[(size_t)s1 * (F / 4) + l16 * 2];
            float4 q1 = x4f[(size_t)s1 * (F / 4) + l16 * 2 + 1];
            a0[0]+=w0*p0.x; a0[1]+=w0*p0.y; a0[2]+=w0*p0.z; a0[3]+=w0*p0.w;
            a0[4]+=w0*q0.x; a0[5]+=w0*q0.y; a0[6]+=w0*q0.z; a0[7]+=w0*q0.w;
            a1[0]+=w1*p1.x; a1[1]+=w1*p1.y; a1[2]+=w1*p1.z; a1[3]+=w1*p1.w;
            a1[4]+=w1*q1.x; a1[5]+=w1*q1.y; a1[6]+=w1*q1.z; a1[7]+=w1*q1.w;
        }
    }
    // tail: one edge per sub-group, stride 4
    for (int e = start + full + g; e < end; e += 4) {
        int s = src_idx[e];
        float l = el[s] + erv;
        l = l > 0.f ? l : NEG_SLOPE * l;
        float w = __expf(l);
        d0 += w;
        if (H) {
            float4 r = x4h[(size_t)s * (F / 8) + l16];
            const __half2* h = reinterpret_cast<const __half2*>(&r);
            #pragma unroll
            for (int k = 0; k < 4; ++k) {
                float2 f = __half22float2(h[k]);
                a0[2*k] += w * f.x;  a0[2*k+1] += w * f.y;
            }
        } else {
            float4 p = x4f[(size_t)s * (F / 4) + l16 * 2];
            float4 q = x4f[(size_t)s * (F / 4) + l16 * 2 + 1];
            a0[0]+=w*p.x; a0[1]+=w*p.y; a0[2]+=w*p.z; a0[3]+=w*p.w;
            a0[4]+=w*q.x; a0[5]+=w*q.y; a0[6]+=w*q.z; a0[7]+=w*q.w;
        }
    }
    #pragma unroll
    for (int k = 0; k < 8; ++k) a0[k] += a1[k];
    d0 += d1;

    // merge 4 sub-groups: xor across lane bits 4 and 5
    #pragma unroll
    for (int k = 0; k < 8; ++k) {
        a0[k] += __shfl_xor(a0[k], 16, 64);
        a0[k] += __shfl_xor(a0[k], 32, 64);
    }
    d0 += __shfl_xor(d0, 16, 64);
    d0 += __shfl_xor(d0, 32, 64);

    if (g == 0) {
        float inv = (count > 0) ? 1.f / d0 : 0.f;
        float4 o0 = make_float4(a0[0]*inv, a0[1]*inv, a0[2]*inv, a0[3]*inv);
        float4 o1 = make_float4(a0[4]*inv, a0[5]*inv, a0[6]*inv, a0[7]*inv);
        float4* dst = reinterpret_cast<float4*>(&out[(size_t)v * F + l16 * 8]);
        dst[0] = o0;
        dst[1] = o1;
    }
}

extern "C" void kernel_launch(void* const* d_in, const int* in_sizes, int n_in,
                              void* d_out, int out_size, void* d_ws, size_t ws_size,
                              hipStream_t stream) {
    const float* x_src   = (const float*)d_in[0];
    const float* x_dst   = (const float*)d_in[1];
    const float* attn_l  = (const float*)d_in[2];
    const float* attn_r  = (const float*)d_in[3];
    const int*   src_idx = (const int*)d_in[4];
    const int*   dst_idx = (const int*)d_in[5];

    int n_src = in_sizes[0] / F;   // 50000
    int n_dst = in_sizes[1] / F;   // 10000
    int E     = in_sizes[4];       // 1600000

    float* out  = (float*)d_out;
    float* el   = (float*)d_ws;                 // n_src floats
    float* er   = el + n_src;                   // n_dst floats
    int*   offs = (int*)(er + n_dst);           // n_dst+1 ints
    uintptr_t p = (uintptr_t)(offs + n_dst + 1);
    p = (p + 15) & ~(uintptr_t)15;              // 16B-align for float4 reads
    __half2* xh = (__half2*)p;                  // n_src * F halves

    size_t need = (p - (uintptr_t)d_ws) + (size_t)n_src * F * sizeof(__half);
    bool fp16ok = ws_size >= need;

    int nlog = (n_src + n_dst + 3) / 4;         // 4 rows (waves) per block
    int noff = (E + 255) / 256;
    prep_kernel<<<nlog + noff, 256, 0, stream>>>(
        x_src, attn_l, el, fp16ok ? xh : nullptr, n_src,
        x_dst, attn_r, er, n_dst, dst_idx, offs, E, nlog);

    int agg_blocks = (n_dst + 3) / 4;           // 4 nodes (waves) per block
    if (fp16ok) {
        gat_aggregate_kernel<true><<<agg_blocks, 256, 0, stream>>>(
            xh, x_src, el, er, src_idx, offs, out, n_dst);
    } else {
        gat_aggregate_kernel<false><<<agg_blocks, 256, 0, stream>>>(
            nullptr, x_src, el, er, src_idx, offs, out, n_dst);
    }
}

// Round 6
// 80.089 us; speedup vs baseline: 1.5279x; 1.0855x over previous
//
#include <hip/hip_runtime.h>
#include <hip/hip_fp16.h>

#define F 128
#define NEG_SLOPE 0.2f
#define NB 8          // src-range buckets (12.8MB fp16 / 8 = 1.6MB per phase, fits 4MB L2)
#define CH 512        // staged edges per chunk
#define NGR 16        // 16 groups x 16 lanes per block

// Fused prep: blocks [0, nlog) -> per-node logits (+fp16 convert of x_src rows);
// blocks [nlog, ...) -> CSR offsets from sorted dst_idx.
__global__ __launch_bounds__(256)
void prep_kernel(const float* __restrict__ x_src, const float* __restrict__ attn_l,
                 float* __restrict__ el, __half2* __restrict__ xh, int n_src,
                 const float* __restrict__ x_dst, const float* __restrict__ attn_r,
                 float* __restrict__ er, int n_dst,
                 const int* __restrict__ dst_idx, int* __restrict__ offs, int E,
                 int nlog) {
    if ((int)blockIdx.x < nlog) {
        int row  = blockIdx.x * 4 + (threadIdx.x >> 6);
        int lane = threadIdx.x & 63;
        if (row < n_src) {
            float2 xv = *reinterpret_cast<const float2*>(&x_src[(size_t)row * F + lane * 2]);
            float2 av = *reinterpret_cast<const float2*>(&attn_l[lane * 2]);
            if (xh) xh[(size_t)row * (F / 2) + lane] = __floats2half2_rn(xv.x, xv.y);
            float s = xv.x * av.x + xv.y * av.y;
            #pragma unroll
            for (int o = 32; o > 0; o >>= 1) s += __shfl_xor(s, o, 64);
            if (lane == 0) el[row] = s;
        } else if (row < n_src + n_dst) {
            int r = row - n_src;
            float2 xv = *reinterpret_cast<const float2*>(&x_dst[(size_t)r * F + lane * 2]);
            float2 av = *reinterpret_cast<const float2*>(&attn_r[lane * 2]);
            float s = xv.x * av.x + xv.y * av.y;
            #pragma unroll
            for (int o = 32; o > 0; o >>= 1) s += __shfl_xor(s, o, 64);
            if (lane == 0) er[r] = s;
        }
    } else {
        int e = ((int)blockIdx.x - nlog) * 256 + threadIdx.x;
        if (e >= E) return;
        int d = dst_idx[e];
        int prev = (e == 0) ? -1 : dst_idx[e - 1];
        for (int v = prev + 1; v <= d; ++v) offs[v] = e;
        if (e == E - 1)
            for (int v = d + 1; v <= n_dst; ++v) offs[v] = E;
    }
}

// One block (256 thr) per dst node. Stage (src, w) in LDS, counting-sort into NB
// src-range buckets, then 16 groups of 16 lanes sweep the bucketed list in order
// (phase-aligned src locality -> L2-resident slices). Lane owns 8 features.
template<bool H>
__global__ __launch_bounds__(256)
void gat_aggregate_kernel(const __half2* __restrict__ xh,
                          const float* __restrict__ x_src,
                          const float* __restrict__ el,
                          const float* __restrict__ er,
                          const int* __restrict__ src_idx,
                          const int* __restrict__ offs,
                          float* __restrict__ out, int bdiv) {
    int v   = blockIdx.x;
    int tid = threadIdx.x;
    int g   = tid >> 4;
    int l16 = tid & 15;

    int start = offs[v];
    int end   = offs[v + 1];
    int count = end - start;
    float erv = er[v];

    __shared__ int   sidx[CH];
    __shared__ float sw[CH];
    __shared__ int   bidx[CH];
    __shared__ float bw[CH];
    __shared__ int   cnt[NB];
    __shared__ int   cur[NB];
    __shared__ float part[4][F];
    __shared__ float pden[4];

    const float4* x4h = reinterpret_cast<const float4*>(xh);     // 16 float4 / row
    const float4* x4f = reinterpret_cast<const float4*>(x_src);  // 32 float4 / row

    float a0[8], a1[8];
    #pragma unroll
    for (int k = 0; k < 8; ++k) { a0[k] = 0.f; a1[k] = 0.f; }
    float d0 = 0.f, d1 = 0.f;

    for (int base = start; base < end; base += CH) {
        int n = min(CH, end - base);
        if (tid < NB) cnt[tid] = 0;
        __syncthreads();

        // stage (src, weight) + bucket histogram
        for (int i = tid; i < n; i += 256) {
            int s = src_idx[base + i];
            float l = el[s] + erv;
            l = l > 0.f ? l : NEG_SLOPE * l;
            sidx[i] = s;
            sw[i]   = __expf(l);
            atomicAdd(&cnt[s / bdiv], 1);
        }
        __syncthreads();
        if (tid < NB) {
            int acc = 0;
            for (int b = 0; b < tid; ++b) acc += cnt[b];
            cur[tid] = acc;
        }
        __syncthreads();
        // scatter into bucket-sorted order
        for (int i = tid; i < n; i += 256) {
            int s = sidx[i];
            int slot = atomicAdd(&cur[s / bdiv], 1);
            bidx[slot] = s;
            bw[slot]   = sw[i];
        }
        __syncthreads();

        // process bucketed list, all groups sweep front-to-back (phase-aligned)
        int full = n & ~(2 * NGR - 1);
        for (int it = 0; it < full; it += 2 * NGR) {
            int s0 = bidx[it + g];
            int s1 = bidx[it + NGR + g];
            float w0 = bw[it + g];
            float w1 = bw[it + NGR + g];
            d0 += w0; d1 += w1;
            if (H) {
                float4 r0 = x4h[(size_t)s0 * (F / 8) + l16];
                float4 r1 = x4h[(size_t)s1 * (F / 8) + l16];
                const __half2* h0 = reinterpret_cast<const __half2*>(&r0);
                const __half2* h1 = reinterpret_cast<const __half2*>(&r1);
                #pragma unroll
                for (int k = 0; k < 4; ++k) {
                    float2 f0 = __half22float2(h0[k]);
                    float2 f1 = __half22float2(h1[k]);
                    a0[2*k]   += w0 * f0.x;  a0[2*k+1] += w0 * f0.y;
                    a1[2*k]   += w1 * f1.x;  a1[2*k+1] += w1 * f1.y;
                }
            } else {
                float4 p0 = x4f[(size_t)s0 * (F/4) + l16*2];
                float4 q0 = x4f[(size_t)s0 * (F/4) + l16*2 + 1];
                float4 p1 = x4f[(size_t)s1 * (F/4) + l16*2];
                float4 q1 = x4f[(size_t)s1 * (F/4) + l16*2 + 1];
                a0[0]+=w0*p0.x; a0[1]+=w0*p0.y; a0[2]+=w0*p0.z; a0[3]+=w0*p0.w;
                a0[4]+=w0*q0.x; a0[5]+=w0*q0.y; a0[6]+=w0*q0.z; a0[7]+=w0*q0.w;
                a1[0]+=w1*p1.x; a1[1]+=w1*p1.y; a1[2]+=w1*p1.z; a1[3]+=w1*p1.w;
                a1[4]+=w1*q1.x; a1[5]+=w1*q1.y; a1[6]+=w1*q1.z; a1[7]+=w1*q1.w;
            }
        }
        for (int it = full + g; it < n; it += NGR) {
            int s  = bidx[it];
            float w = bw[it];
            d0 += w;
            if (H) {
                float4 r = x4h[(size_t)s * (F / 8) + l16];
                const __half2* h = reinterpret_cast<const __half2*>(&r);
                #pragma unroll
                for (int k = 0; k < 4; ++k) {
                    float2 f = __half22float2(h[k]);
                    a0[2*k] += w * f.x;  a0[2*k+1] += w * f.y;
                }
            } else {
                float4 p = x4f[(size_t)s * (F/4) + l16*2];
                float4 q = x4f[(size_t)s * (F/4) + l16*2 + 1];
                a0[0]+=w*p.x; a0[1]+=w*p.y; a0[2]+=w*p.z; a0[3]+=w*p.w;
                a0[4]+=w*q.x; a0[5]+=w*q.y; a0[6]+=w*q.z; a0[7]+=w*q.w;
            }
        }
        __syncthreads();   // protect sidx/sw before next chunk's staging
    }

    #pragma unroll
    for (int k = 0; k < 8; ++k) a0[k] += a1[k];
    d0 += d1;

    // merge the 4 groups within each wave
    #pragma unroll
    for (int k = 0; k < 8; ++k) {
        a0[k] += __shfl_xor(a0[k], 16, 64);
        a0[k] += __shfl_xor(a0[k], 32, 64);
    }
    d0 += __shfl_xor(d0, 16, 64);
    d0 += __shfl_xor(d0, 32, 64);

    int wid  = tid >> 6;
    int lane = tid & 63;
    if ((lane >> 4) == 0) {
        #pragma unroll
        for (int k = 0; k < 8; ++k) part[wid][l16 * 8 + k] = a0[k];
        if (l16 == 0) pden[wid] = d0;
    }
    __syncthreads();

    if (tid < F) {
        float t = 0.f, dd = 0.f;
        #pragma unroll
        for (int w = 0; w < 4; ++w) { t += part[w][tid]; dd += pden[w]; }
        out[(size_t)v * F + tid] = (count > 0) ? t / dd : 0.f;
    }
}

extern "C" void kernel_launch(void* const* d_in, const int* in_sizes, int n_in,
                              void* d_out, int out_size, void* d_ws, size_t ws_size,
                              hipStream_t stream) {
    const float* x_src   = (const float*)d_in[0];
    const float* x_dst   = (const float*)d_in[1];
    const float* attn_l  = (const float*)d_in[2];
    const float* attn_r  = (const float*)d_in[3];
    const int*   src_idx = (const int*)d_in[4];
    const int*   dst_idx = (const int*)d_in[5];

    int n_src = in_sizes[0] / F;   // 50000
    int n_dst = in_sizes[1] / F;   // 10000
    int E     = in_sizes[4];       // 1600000

    float* out  = (float*)d_out;
    float* el   = (float*)d_ws;                 // n_src floats
    float* er   = el + n_src;                   // n_dst floats
    int*   offs = (int*)(er + n_dst);           // n_dst+1 ints
    uintptr_t p = (uintptr_t)(offs + n_dst + 1);
    p = (p + 15) & ~(uintptr_t)15;              // 16B-align for float4 reads
    __half2* xh = (__half2*)p;                  // n_src * F halves

    size_t need = (p - (uintptr_t)d_ws) + (size_t)n_src * F * sizeof(__half);
    bool fp16ok = ws_size >= need;

    int nlog = (n_src + n_dst + 3) / 4;         // 4 rows (waves) per block
    int noff = (E + 255) / 256;
    prep_kernel<<<nlog + noff, 256, 0, stream>>>(
        x_src, attn_l, el, fp16ok ? xh : nullptr, n_src,
        x_dst, attn_r, er, n_dst, dst_idx, offs, E, nlog);

    int bdiv = (n_src + NB - 1) / NB;           // src rows per bucket
    if (fp16ok) {
        gat_aggregate_kernel<true><<<n_dst, 256, 0, stream>>>(
            xh, x_src, el, er, src_idx, offs, out, bdiv);
    } else {
        gat_aggregate_kernel<false><<<n_dst, 256, 0, stream>>>(
            nullptr, x_src, el, er, src_idx, offs, out, bdiv);
    }
}